// Round 1
// baseline (1606.448 us; speedup 1.0000x reference)
//
#include <hip/hip_runtime.h>

// Problem constants (also derived from in_sizes at launch)
static constexpr int F_IN = 128;
static constexpr int H1 = 32;
static constexpr int H2 = 64;
static constexpr int H3 = 128;
static constexpr int TPB = 256;

// ---------------- degree / dinv ----------------
__global__ void deg_kernel(const int* __restrict__ dst, float* __restrict__ deg, int E) {
    for (int i = blockIdx.x * blockDim.x + threadIdx.x; i < E; i += gridDim.x * blockDim.x)
        atomicAdd(&deg[dst[i]], 1.0f);
}

__global__ void dinv_kernel(float* __restrict__ d, int N) {
    int i = blockIdx.x * blockDim.x + threadIdx.x;
    if (i < N) d[i] = 1.0f / sqrtf(d[i] + 1.0f);   // deg incl. self-loop
}

// ---------------- dense GEMM: Hout[N,FOUT] = (relu?)X[N,FIN] @ W[FIN,FOUT] ----------------
template <int FIN, int FOUT, bool RELU_IN>
__global__ void gemm_kernel(const float* __restrict__ X, const float* __restrict__ W,
                            float* __restrict__ Hout, int N) {
    __shared__ float Ws[FIN * FOUT];
    for (int t = threadIdx.x; t < FIN * FOUT; t += blockDim.x) Ws[t] = W[t];
    __syncthreads();
    constexpr int ROWS = TPB / FOUT;          // rows per block
    const int c = threadIdx.x % FOUT;
    const int r = threadIdx.x / FOUT;
    for (int base = blockIdx.x * ROWS; base < N; base += gridDim.x * ROWS) {
        int row = base + r;
        if (row >= N) continue;
        const float* xr = X + (long)row * FIN;
        float acc = 0.0f;
#pragma unroll
        for (int k = 0; k < FIN; ++k) {
            float xv = xr[k];
            if (RELU_IN) xv = fmaxf(xv, 0.0f);
            acc = fmaf(xv, Ws[k * FOUT + c], acc);
        }
        Hout[(long)row * FOUT + c] = acc;
    }
}

// ---------------- G = H * dinv^2 + b  (self-loop + bias init) ----------------
template <int F>
__global__ void init_kernel(const float* __restrict__ H, const float* __restrict__ dinv,
                            const float* __restrict__ b, float* __restrict__ G, int N) {
    const unsigned total = (unsigned)N * F;
    for (unsigned t = blockIdx.x * blockDim.x + threadIdx.x; t < total;
         t += gridDim.x * blockDim.x) {
        unsigned i = t / F;
        unsigned f = t % F;
        float d = dinv[i];
        G[t] = H[t] * d * d + b[f];
    }
}

// ---------------- edge scatter: G[dst] += H[src] * dinv[src]*dinv[dst] ----------------
template <int F>
__global__ void scatter_kernel(const int* __restrict__ src, const int* __restrict__ dst,
                               const float* __restrict__ dinv, const float* __restrict__ H,
                               float* __restrict__ G, int E) {
    const unsigned total = (unsigned)E * F;
    for (unsigned t = blockIdx.x * blockDim.x + threadIdx.x; t < total;
         t += gridDim.x * blockDim.x) {
        unsigned e = t / F;
        unsigned f = t % F;
        int s = src[e], d = dst[e];
        float coef = dinv[s] * dinv[d];
        atomicAdd(&G[(unsigned)d * F + f], H[(unsigned)s * F + f] * coef);
    }
}

// ---------------- pooling ----------------
__global__ void pool_kernel(const float* __restrict__ G3, const int* __restrict__ batch,
                            float* __restrict__ sums, int N) {
    const unsigned total = (unsigned)N * 128;
    for (unsigned t = blockIdx.x * blockDim.x + threadIdx.x; t < total;
         t += gridDim.x * blockDim.x) {
        unsigned i = t >> 7;
        unsigned f = t & 127;
        atomicAdd(&sums[(unsigned)batch[i] * 128 + f], G3[t]);
    }
}

__global__ void cnt_kernel(const int* __restrict__ batch, float* __restrict__ cnt, int N) {
    int i = blockIdx.x * blockDim.x + threadIdx.x;
    if (i < N) atomicAdd(&cnt[batch[i]], 1.0f);
}

// ---------------- final: out[g] = (sums[g,:]/max(cnt,1)) . W_lin + b_lin ----------------
__global__ void final_kernel(const float* __restrict__ sums, const float* __restrict__ cnt,
                             const float* __restrict__ Wl, const float* __restrict__ bl,
                             float* __restrict__ out) {
    int g = blockIdx.x;
    int f = threadIdx.x;  // 128 threads = 2 waves
    float c = fmaxf(cnt[g], 1.0f);
    float v = (sums[(unsigned)g * 128 + f] / c) * Wl[f];
#pragma unroll
    for (int o = 32; o > 0; o >>= 1) v += __shfl_down(v, o);
    __shared__ float red[2];
    if ((threadIdx.x & 63) == 0) red[threadIdx.x >> 6] = v;
    __syncthreads();
    if (threadIdx.x == 0) out[g] = red[0] + red[1] + bl[0];
}

static inline int grid_for(unsigned total, int cap = 8192) {
    unsigned g = (total + TPB - 1) / TPB;
    return (int)(g < (unsigned)cap ? g : (unsigned)cap);
}

extern "C" void kernel_launch(void* const* d_in, const int* in_sizes, int n_in,
                              void* d_out, int out_size, void* d_ws, size_t ws_size,
                              hipStream_t stream) {
    const float* x     = (const float*)d_in[0];
    const int*   ei    = (const int*)d_in[1];
    const int*   batch = (const int*)d_in[2];
    const float* W1    = (const float*)d_in[3];
    const float* b1    = (const float*)d_in[4];
    const float* W2    = (const float*)d_in[5];
    const float* b2    = (const float*)d_in[6];
    const float* W3    = (const float*)d_in[7];
    const float* b3    = (const float*)d_in[8];
    const float* Wl    = (const float*)d_in[9];
    const float* bl    = (const float*)d_in[10];
    float* out = (float*)d_out;

    const int N = in_sizes[0] / F_IN;       // 100000
    const int E = in_sizes[1] / 2;          // 1600000
    const int G = out_size;                 // 1024
    const int* src = ei;
    const int* dst = ei + E;

    // workspace layout (floats)
    float* dinv = (float*)d_ws;             // N
    float* bufA = dinv + N;                 // N*128 (h)
    float* bufB = bufA + (size_t)N * 128;   // N*128 (aggregated)
    float* sums = bufB + (size_t)N * 128;   // G*128
    float* cnt  = sums + (size_t)G * 128;   // G

    // 1) degree (with self-loop) -> dinv, in place
    hipMemsetAsync(dinv, 0, (size_t)N * sizeof(float), stream);
    deg_kernel<<<grid_for(E), TPB, 0, stream>>>(dst, dinv, E);
    dinv_kernel<<<(N + TPB - 1) / TPB, TPB, 0, stream>>>(dinv, N);

    // 2) layer 1: h = x@W1 ; g = scatter + selfloop + b1 ; relu fused into next gemm
    gemm_kernel<F_IN, H1, false><<<grid_for((unsigned)N * H1), TPB, 0, stream>>>(x, W1, bufA, N);
    init_kernel<H1><<<grid_for((unsigned)N * H1), TPB, 0, stream>>>(bufA, dinv, b1, bufB, N);
    scatter_kernel<H1><<<grid_for((unsigned)E * H1), TPB, 0, stream>>>(src, dst, dinv, bufA, bufB, E);

    // 3) layer 2
    gemm_kernel<H1, H2, true><<<grid_for((unsigned)N * H2), TPB, 0, stream>>>(bufB, W2, bufA, N);
    init_kernel<H2><<<grid_for((unsigned)N * H2), TPB, 0, stream>>>(bufA, dinv, b2, bufB, N);
    scatter_kernel<H2><<<grid_for((unsigned)E * H2), TPB, 0, stream>>>(src, dst, dinv, bufA, bufB, E);

    // 4) layer 3 (no relu after)
    gemm_kernel<H2, H3, true><<<grid_for((unsigned)N * H3), TPB, 0, stream>>>(bufB, W3, bufA, N);
    init_kernel<H3><<<grid_for((unsigned)N * H3), TPB, 0, stream>>>(bufA, dinv, b3, bufB, N);
    scatter_kernel<H3><<<grid_for((unsigned)E * H3), TPB, 0, stream>>>(src, dst, dinv, bufA, bufB, E);

    // 5) pool: mean over batch ids
    hipMemsetAsync(sums, 0, (size_t)(G * 128 + G) * sizeof(float), stream);
    pool_kernel<<<grid_for((unsigned)N * 128), TPB, 0, stream>>>(bufB, batch, sums, N);
    cnt_kernel<<<(N + TPB - 1) / TPB, TPB, 0, stream>>>(batch, cnt, N);

    // 6) final linear
    final_kernel<<<G, 128, 0, stream>>>(sums, cnt, Wl, bl, out);
}